// Round 1
// baseline (423.691 us; speedup 1.0000x reference)
//
#include <hip/hip_runtime.h>
#include <hip/hip_bf16.h>

typedef _Float16 half8 __attribute__((ext_vector_type(8)));
typedef float f32x4 __attribute__((ext_vector_type(4)));

#define B_ 16
#define C_ 256
#define D_ 128
#define H_ 64
#define W_ 64
#define N_ 4096   // H*W
#define M_ 1024   // (H/2)*(W/2)

// workspace layout (bytes)
static constexpr size_t WS_PHI   = 0;                                  // fp16 [B][M][C]   8 MB
static constexpr size_t WS_GPOOL = WS_PHI   + (size_t)B_*M_*C_*2;      // fp16 [B][D][M]   4 MB
static constexpr size_t WS_Y     = WS_GPOOL + (size_t)B_*D_*M_*2;      // f32  [B][N][D]  32 MB
static constexpr size_t WS_BNSUM = WS_Y     + (size_t)B_*N_*D_*4;      // f32  [C]
static constexpr size_t WS_BNSSQ = WS_BNSUM + (size_t)C_*4;            // f32  [C]

// ---------------------------------------------------------------------------
// P1: phi = fp16(maxpool2x2(x)), layout [B][M][C] (C contiguous for MFMA B-frags)
// grid (32 pooled-rows, 16 batches), 256 threads
// ---------------------------------------------------------------------------
__global__ __launch_bounds__(256) void pool_phi_kernel(
    const float* __restrict__ x, _Float16* __restrict__ phi) {
  const int i = blockIdx.x;            // pooled row 0..31
  const int b = blockIdx.y;
  const int t = threadIdx.x;
  __shared__ _Float16 tile[32][264];   // [m-col][c], padded pitch

  const int j2  = t & 31;              // pooled col
  const int cg0 = t >> 5;              // 0..7
#pragma unroll 4
  for (int it = 0; it < 32; ++it) {
    const int c = it*8 + cg0;
    const float* base = x + (((size_t)b*C_ + c)*H_ + 2*i)*W_ + 2*j2;
    float2 r0 = *(const float2*)base;
    float2 r1 = *(const float2*)(base + W_);
    float p = fmaxf(fmaxf(r0.x, r0.y), fmaxf(r1.x, r1.y));
    tile[j2][c] = (_Float16)p;
  }
  __syncthreads();
  const int m  = t >> 3;               // 0..31
  const int cg = (t & 7) * 32;
  const uint4* src = (const uint4*)&tile[m][cg];
  uint4* dst = (uint4*)(phi + ((size_t)b*M_ + i*32 + m)*C_ + cg);
#pragma unroll
  for (int q = 0; q < 4; ++q) dst[q] = src[q];
}

// ---------------------------------------------------------------------------
// P2: gpool[b][d][m] = fp16( maxpool2x2( x *. g_w ) + g_b )
// Swapped-orientation MFMA: A = g_w rows (d), B = x columns (n).
// D-frag: col=n=lane&15, row=d=(lane>>4)*4+r  -> pooling pairs are lane pairs.
// grid (32 row-pairs, 16 batches), 256 threads (4 waves; wave covers 2 d-subtiles x 8 n-subtiles)
// ---------------------------------------------------------------------------
__global__ __launch_bounds__(256) void gconv_pool_kernel(
    const float* __restrict__ x, const float* __restrict__ g_w,
    const float* __restrict__ g_b, _Float16* __restrict__ gpool) {
  const int i = blockIdx.x;            // image row-pair (rows 2i, 2i+1)
  const int b = blockIdx.y;
  const int t = threadIdx.x;
  const int w = t >> 6, l = t & 63, g = l >> 4, c16 = l & 15;
  const float* xb = x + (size_t)b*C_*N_;

  f32x4 acc[2][8];
#pragma unroll
  for (int a = 0; a < 2; ++a)
#pragma unroll
    for (int n = 0; n < 8; ++n) acc[a][n] = (f32x4){0.f,0.f,0.f,0.f};

#pragma unroll 2
  for (int kk = 0; kk < 8; ++kk) {
    const int c0 = kk*32 + g*8;
    half8 af[2];
#pragma unroll
    for (int ds = 0; ds < 2; ++ds) {
      const int d = (w*2 + ds)*16 + c16;
      const float4* gw = (const float4*)(g_w + (size_t)d*C_ + c0);
      float4 u0 = gw[0], u1 = gw[1];
      half8 a;
      a[0]=(_Float16)u0.x; a[1]=(_Float16)u0.y; a[2]=(_Float16)u0.z; a[3]=(_Float16)u0.w;
      a[4]=(_Float16)u1.x; a[5]=(_Float16)u1.y; a[6]=(_Float16)u1.z; a[7]=(_Float16)u1.w;
      af[ds] = a;
    }
#pragma unroll
    for (int ns = 0; ns < 8; ++ns) {
      const int nn = i*128 + ns*16 + c16;
      half8 bf;
#pragma unroll
      for (int j = 0; j < 8; ++j) bf[j] = (_Float16)xb[(size_t)(c0 + j)*N_ + nn];
      acc[0][ns] = __builtin_amdgcn_mfma_f32_16x16x32_f16(af[0], bf, acc[0][ns], 0, 0, 0);
      acc[1][ns] = __builtin_amdgcn_mfma_f32_16x16x32_f16(af[1], bf, acc[1][ns], 0, 0, 0);
    }
  }

  // 2x2 pool: vertical = nsub s vs s+4 (rows 2i vs 2i+1), horizontal = lane pair
#pragma unroll
  for (int ds = 0; ds < 2; ++ds) {
#pragma unroll
    for (int r = 0; r < 4; ++r) {
      const int d = (w*2 + ds)*16 + g*4 + r;
      const float gb = g_b[d];
#pragma unroll
      for (int s = 0; s < 4; ++s) {
        float v = fmaxf(acc[ds][s][r], acc[ds][s+4][r]);
        v = fmaxf(v, __shfl_xor(v, 1, 64));
        if ((l & 1) == 0) {
          const int m = i*32 + s*8 + (c16 >> 1);
          gpool[((size_t)b*D_ + d)*M_ + m] = (_Float16)(v + gb);
        }
      }
    }
  }
}

// ---------------------------------------------------------------------------
// P3: flash attention. Block = (batch, 64 q-rows), 4 waves x 16 rows.
// Q resident in registers (fp16 frags built from strided-but-coalesced x reads).
// Per 32-key chunk: stage phi/gpool in padded LDS, QK^T (16 MFMA), wave-parallel
// online softmax, P->LDS roundtrip, PV (8 MFMA). y[b][n][d] f32 out.
// ---------------------------------------------------------------------------
__global__ __launch_bounds__(256) void attn_kernel(
    const float* __restrict__ x, const _Float16* __restrict__ phi,
    const _Float16* __restrict__ gpool, float* __restrict__ y) {
  const int nt = blockIdx.x;           // 0..63
  const int b  = blockIdx.y;
  const int t  = threadIdx.x;
  const int w = t >> 6, l = t & 63, g = l >> 4, c16 = l & 15;
  const int nw = nt*64 + w*16;

  __shared__ _Float16 phi_s[32][264];  // [m][c], padded (pitch 528B: 16 lanes -> 2-way banks)
  __shared__ _Float16 gp_s[128][40];   // [d][m], padded (pitch 80B)
  __shared__ _Float16 p_s[4][16][40];  // per-wave P tile [n][m], padded

  // Q fragments: rows nw..nw+15, K=256 in 8 steps
  half8 qf[8];
  {
    const int nq = nw + c16;
#pragma unroll
    for (int kk = 0; kk < 8; ++kk) {
      const int cb = kk*32 + g*8;
      half8 q;
#pragma unroll
      for (int j = 0; j < 8; ++j) q[j] = (_Float16)x[((size_t)b*C_ + cb + j)*N_ + nq];
      qf[kk] = q;
    }
  }

  float m_run[4], l_run[4];
#pragma unroll
  for (int r = 0; r < 4; ++r) { m_run[r] = -INFINITY; l_run[r] = 0.f; }
  f32x4 yacc[8];
#pragma unroll
  for (int d = 0; d < 8; ++d) yacc[d] = (f32x4){0.f,0.f,0.f,0.f};

  for (int ch = 0; ch < 32; ++ch) {
    const int m0 = ch*32;
    __syncthreads();
    {
      // stage phi chunk [32 m][256 c]
      const int mr = t >> 3, cgb = (t & 7)*32;
      const uint4* src = (const uint4*)(phi + ((size_t)b*M_ + m0 + mr)*C_ + cgb);
      uint4* dst = (uint4*)&phi_s[mr][cgb];
      dst[0] = src[0]; dst[1] = src[1]; dst[2] = src[2]; dst[3] = src[3];
      // stage gpool chunk [128 d][32 m]
      const int dr = t >> 1, mh = (t & 1)*16;
      const uint4* s2 = (const uint4*)(gpool + ((size_t)b*D_ + dr)*M_ + m0 + mh);
      uint4* d2 = (uint4*)&gp_s[dr][mh];
      d2[0] = s2[0]; d2[1] = s2[1];
    }
    __syncthreads();

    // QK^T: f tiles for m0..m0+15 and m0+16..m0+31
    f32x4 f0 = {0.f,0.f,0.f,0.f}, f1 = {0.f,0.f,0.f,0.f};
#pragma unroll
    for (int kk = 0; kk < 8; ++kk) {
      const int cb = kk*32 + g*8;
      f0 = __builtin_amdgcn_mfma_f32_16x16x32_f16(qf[kk], *(const half8*)&phi_s[c16][cb], f0, 0, 0, 0);
      f1 = __builtin_amdgcn_mfma_f32_16x16x32_f16(qf[kk], *(const half8*)&phi_s[16 + c16][cb], f1, 0, 0, 0);
    }

    // online softmax (rows live at (g,r); reduce across the 16 m-lanes)
    float sc[4];
#pragma unroll
    for (int r = 0; r < 4; ++r) {
      float cm = fmaxf(f0[r], f1[r]);
      cm = fmaxf(cm, __shfl_xor(cm, 1, 64));
      cm = fmaxf(cm, __shfl_xor(cm, 2, 64));
      cm = fmaxf(cm, __shfl_xor(cm, 4, 64));
      cm = fmaxf(cm, __shfl_xor(cm, 8, 64));
      const float mn = fmaxf(m_run[r], cm);
      sc[r] = __expf(m_run[r] - mn);
      const float p0 = __expf(f0[r] - mn);
      const float p1 = __expf(f1[r] - mn);
      float rs = p0 + p1;
      rs += __shfl_xor(rs, 1, 64);
      rs += __shfl_xor(rs, 2, 64);
      rs += __shfl_xor(rs, 4, 64);
      rs += __shfl_xor(rs, 8, 64);
      l_run[r] = l_run[r]*sc[r] + rs;
      m_run[r] = mn;
      f0[r] = p0; f1[r] = p1;
    }
#pragma unroll
    for (int d = 0; d < 8; ++d)
#pragma unroll
      for (int r = 0; r < 4; ++r) yacc[d][r] *= sc[r];

    // P -> LDS (wave-private), then read back as PV A-fragment
#pragma unroll
    for (int r = 0; r < 4; ++r) {
      p_s[w][g*4 + r][c16]      = (_Float16)f0[r];
      p_s[w][g*4 + r][16 + c16] = (_Float16)f1[r];
    }
    asm volatile("s_waitcnt lgkmcnt(0)" ::: "memory");
    __builtin_amdgcn_sched_barrier(0);
    const half8 pa = *(const half8*)&p_s[w][c16][g*8];
#pragma unroll
    for (int ds = 0; ds < 8; ++ds)
      yacc[ds] = __builtin_amdgcn_mfma_f32_16x16x32_f16(pa, *(const half8*)&gp_s[ds*16 + c16][g*8], yacc[ds], 0, 0, 0);
  }

  // epilogue: y = yacc / l
#pragma unroll
  for (int r = 0; r < 4; ++r) {
    const float inv = 1.0f / l_run[r];
    float* yr = y + ((size_t)b*N_ + nw + g*4 + r)*D_ + c16;
#pragma unroll
    for (int ds = 0; ds < 8; ++ds) yr[ds*16] = yacc[ds][r] * inv;
  }
}

// ---------------------------------------------------------------------------
// P4a: W-conv (recompute) -> per-channel sum/sumsq partials via atomics.
// Swapped orientation: A = w_w rows (c), B = y^T cols (n). grid (64 n-tiles, 16 b)
// ---------------------------------------------------------------------------
__global__ __launch_bounds__(256) void wconv_stats_kernel(
    const float* __restrict__ y, const float* __restrict__ w_w,
    const float* __restrict__ w_b, float* __restrict__ bnsum,
    float* __restrict__ bnssq) {
  const int nt = blockIdx.x, b = blockIdx.y, t = threadIdx.x;
  const int w = t >> 6, l = t & 63, g = l >> 4, c16 = l & 15;
  const int n0 = nt*64;

  f32x4 acc[4][4];
#pragma unroll
  for (int a = 0; a < 4; ++a)
#pragma unroll
    for (int n = 0; n < 4; ++n) acc[a][n] = (f32x4){0.f,0.f,0.f,0.f};

#pragma unroll
  for (int kk = 0; kk < 4; ++kk) {
    const int d0 = kk*32 + g*8;
    half8 af[4];
#pragma unroll
    for (int cs = 0; cs < 4; ++cs) {
      const int c = w*64 + cs*16 + c16;
      const float4* p = (const float4*)(w_w + (size_t)c*D_ + d0);
      float4 u0 = p[0], u1 = p[1];
      half8 a;
      a[0]=(_Float16)u0.x; a[1]=(_Float16)u0.y; a[2]=(_Float16)u0.z; a[3]=(_Float16)u0.w;
      a[4]=(_Float16)u1.x; a[5]=(_Float16)u1.y; a[6]=(_Float16)u1.z; a[7]=(_Float16)u1.w;
      af[cs] = a;
    }
#pragma unroll
    for (int ns = 0; ns < 4; ++ns) {
      const int nn = n0 + ns*16 + c16;
      const float4* p = (const float4*)(y + ((size_t)b*N_ + nn)*D_ + d0);
      float4 u0 = p[0], u1 = p[1];
      half8 bf;
      bf[0]=(_Float16)u0.x; bf[1]=(_Float16)u0.y; bf[2]=(_Float16)u0.z; bf[3]=(_Float16)u0.w;
      bf[4]=(_Float16)u1.x; bf[5]=(_Float16)u1.y; bf[6]=(_Float16)u1.z; bf[7]=(_Float16)u1.w;
#pragma unroll
      for (int cs = 0; cs < 4; ++cs)
        acc[cs][ns] = __builtin_amdgcn_mfma_f32_16x16x32_f16(af[cs], bf, acc[cs][ns], 0, 0, 0);
    }
  }

#pragma unroll
  for (int cs = 0; cs < 4; ++cs) {
#pragma unroll
    for (int r = 0; r < 4; ++r) {
      const int c = w*64 + cs*16 + g*4 + r;
      const float wb = w_b[c];
      float s = 0.f, q = 0.f;
#pragma unroll
      for (int ns = 0; ns < 4; ++ns) {
        const float v = acc[cs][ns][r] + wb;
        s += v; q += v*v;
      }
      s += __shfl_xor(s, 1, 64); s += __shfl_xor(s, 2, 64);
      s += __shfl_xor(s, 4, 64); s += __shfl_xor(s, 8, 64);
      q += __shfl_xor(q, 1, 64); q += __shfl_xor(q, 2, 64);
      q += __shfl_xor(q, 4, 64); q += __shfl_xor(q, 8, 64);
      if (c16 == 0) { atomicAdd(&bnsum[c], s); atomicAdd(&bnssq[c], q); }
    }
  }
}

// ---------------------------------------------------------------------------
// P4b: W-conv recompute + BatchNorm + residual add -> out[b][c][n]
// ---------------------------------------------------------------------------
__global__ __launch_bounds__(256) void wconv_bn_kernel(
    const float* __restrict__ y, const float* __restrict__ w_w,
    const float* __restrict__ w_b, const float* __restrict__ bnsum,
    const float* __restrict__ bnssq, const float* __restrict__ gamma,
    const float* __restrict__ beta, const float* __restrict__ x,
    float* __restrict__ out) {
  const int nt = blockIdx.x, b = blockIdx.y, t = threadIdx.x;
  const int w = t >> 6, l = t & 63, g = l >> 4, c16 = l & 15;
  const int n0 = nt*64;

  f32x4 acc[4][4];
#pragma unroll
  for (int a = 0; a < 4; ++a)
#pragma unroll
    for (int n = 0; n < 4; ++n) acc[a][n] = (f32x4){0.f,0.f,0.f,0.f};

#pragma unroll
  for (int kk = 0; kk < 4; ++kk) {
    const int d0 = kk*32 + g*8;
    half8 af[4];
#pragma unroll
    for (int cs = 0; cs < 4; ++cs) {
      const int c = w*64 + cs*16 + c16;
      const float4* p = (const float4*)(w_w + (size_t)c*D_ + d0);
      float4 u0 = p[0], u1 = p[1];
      half8 a;
      a[0]=(_Float16)u0.x; a[1]=(_Float16)u0.y; a[2]=(_Float16)u0.z; a[3]=(_Float16)u0.w;
      a[4]=(_Float16)u1.x; a[5]=(_Float16)u1.y; a[6]=(_Float16)u1.z; a[7]=(_Float16)u1.w;
      af[cs] = a;
    }
#pragma unroll
    for (int ns = 0; ns < 4; ++ns) {
      const int nn = n0 + ns*16 + c16;
      const float4* p = (const float4*)(y + ((size_t)b*N_ + nn)*D_ + d0);
      float4 u0 = p[0], u1 = p[1];
      half8 bf;
      bf[0]=(_Float16)u0.x; bf[1]=(_Float16)u0.y; bf[2]=(_Float16)u0.z; bf[3]=(_Float16)u0.w;
      bf[4]=(_Float16)u1.x; bf[5]=(_Float16)u1.y; bf[6]=(_Float16)u1.z; bf[7]=(_Float16)u1.w;
#pragma unroll
      for (int cs = 0; cs < 4; ++cs)
        acc[cs][ns] = __builtin_amdgcn_mfma_f32_16x16x32_f16(af[cs], bf, acc[cs][ns], 0, 0, 0);
    }
  }

  const float inv_cnt = 1.0f / (float)((size_t)B_ * N_);
#pragma unroll
  for (int cs = 0; cs < 4; ++cs) {
#pragma unroll
    for (int r = 0; r < 4; ++r) {
      const int c = w*64 + cs*16 + g*4 + r;
      const float wb  = w_b[c];
      const float mean = bnsum[c] * inv_cnt;
      const float var  = bnssq[c] * inv_cnt - mean*mean;
      const float istd = rsqrtf(var + 1e-5f);
      const float ga = gamma[c], be = beta[c];
#pragma unroll
      for (int ns = 0; ns < 4; ++ns) {
        const int n = n0 + ns*16 + c16;
        const size_t idx = ((size_t)b*C_ + c)*N_ + n;
        const float v = acc[cs][ns][r] + wb;
        out[idx] = (v - mean)*istd*ga + be + x[idx];
      }
    }
  }
}

// ---------------------------------------------------------------------------
extern "C" void kernel_launch(void* const* d_in, const int* in_sizes, int n_in,
                              void* d_out, int out_size, void* d_ws, size_t ws_size,
                              hipStream_t stream) {
  const float* x     = (const float*)d_in[0];
  const float* g_w   = (const float*)d_in[1];
  const float* g_b   = (const float*)d_in[2];
  const float* w_w   = (const float*)d_in[3];
  const float* w_b   = (const float*)d_in[4];
  const float* gamma = (const float*)d_in[5];
  const float* beta  = (const float*)d_in[6];
  float* out = (float*)d_out;

  char* ws = (char*)d_ws;
  _Float16* phi   = (_Float16*)(ws + WS_PHI);
  _Float16* gpool = (_Float16*)(ws + WS_GPOOL);
  float*    yb    = (float*)(ws + WS_Y);
  float*    bnsum = (float*)(ws + WS_BNSUM);
  float*    bnssq = (float*)(ws + WS_BNSSQ);

  pool_phi_kernel<<<dim3(32, 16), 256, 0, stream>>>(x, phi);
  gconv_pool_kernel<<<dim3(32, 16), 256, 0, stream>>>(x, g_w, g_b, gpool);
  attn_kernel<<<dim3(64, 16), 256, 0, stream>>>(x, phi, gpool, yb);
  hipMemsetAsync(bnsum, 0, 2*C_*sizeof(float), stream);
  wconv_stats_kernel<<<dim3(64, 16), 256, 0, stream>>>(yb, w_w, w_b, bnsum, bnssq);
  wconv_bn_kernel<<<dim3(64, 16), 256, 0, stream>>>(yb, w_w, w_b, bnsum, bnssq, gamma, beta, x, out);
}

// Round 2
// 373.801 us; speedup vs baseline: 1.1335x; 1.1335x over previous
//
#include <hip/hip_runtime.h>
#include <hip/hip_bf16.h>

typedef _Float16 half8 __attribute__((ext_vector_type(8)));
typedef float f32x4 __attribute__((ext_vector_type(4)));

#define B_ 16
#define C_ 256
#define D_ 128
#define H_ 64
#define W_ 64
#define N_ 4096   // H*W
#define M_ 1024   // (H/2)*(W/2)
#define NCH 32    // M/32 key chunks

// workspace layout (bytes)
static constexpr size_t WS_PHI   = 0;                                  // fp16 [B][M][C]   8 MB
static constexpr size_t WS_GPOOL = WS_PHI   + (size_t)B_*M_*C_*2;      // fp16 [B][D][M]   4 MB
static constexpr size_t WS_Y     = WS_GPOOL + (size_t)B_*D_*M_*2;      // fp16 [B][N][D]  16 MB
static constexpr size_t WS_BNSUM = WS_Y     + (size_t)B_*N_*D_*2;      // f32  [C]
static constexpr size_t WS_BNSSQ = WS_BNSUM + (size_t)C_*4;            // f32  [C]

typedef __attribute__((address_space(3))) void lds_vt;
typedef const __attribute__((address_space(1))) void gbl_vt;

__device__ __forceinline__ void gl2lds16(const void* g, void* s) {
  __builtin_amdgcn_global_load_lds((gbl_vt*)g, (lds_vt*)s, 16, 0, 0);
}

// ---------------------------------------------------------------------------
// P1: phi = fp16(maxpool2x2(x)), layout [B][M][C]
// ---------------------------------------------------------------------------
__global__ __launch_bounds__(256) void pool_phi_kernel(
    const float* __restrict__ x, _Float16* __restrict__ phi) {
  const int i = blockIdx.x;            // pooled row 0..31
  const int b = blockIdx.y;
  const int t = threadIdx.x;
  __shared__ _Float16 tile[32][264];

  const int j2  = t & 31;              // pooled col
  const int cg0 = t >> 5;              // 0..7
#pragma unroll 4
  for (int it = 0; it < 32; ++it) {
    const int c = it*8 + cg0;
    const float* base = x + (((size_t)b*C_ + c)*H_ + 2*i)*W_ + 2*j2;
    float2 r0 = *(const float2*)base;
    float2 r1 = *(const float2*)(base + W_);
    float p = fmaxf(fmaxf(r0.x, r0.y), fmaxf(r1.x, r1.y));
    tile[j2][c] = (_Float16)p;
  }
  __syncthreads();
  const int m  = t >> 3;
  const int cg = (t & 7) * 32;
  const uint4* src = (const uint4*)&tile[m][cg];
  uint4* dst = (uint4*)(phi + ((size_t)b*M_ + i*32 + m)*C_ + cg);
#pragma unroll
  for (int q = 0; q < 4; ++q) dst[q] = src[q];
}

// ---------------------------------------------------------------------------
// P2: gpool[b][d][m] = fp16( maxpool2x2( x *. g_w ) + g_b )
// ---------------------------------------------------------------------------
__global__ __launch_bounds__(256) void gconv_pool_kernel(
    const float* __restrict__ x, const float* __restrict__ g_w,
    const float* __restrict__ g_b, _Float16* __restrict__ gpool) {
  const int i = blockIdx.x;            // image row-pair
  const int b = blockIdx.y;
  const int t = threadIdx.x;
  const int w = t >> 6, l = t & 63, g = l >> 4, c16 = l & 15;
  const float* xb = x + (size_t)b*C_*N_;

  f32x4 acc[2][8];
#pragma unroll
  for (int a = 0; a < 2; ++a)
#pragma unroll
    for (int n = 0; n < 8; ++n) acc[a][n] = (f32x4){0.f,0.f,0.f,0.f};

#pragma unroll 2
  for (int kk = 0; kk < 8; ++kk) {
    const int c0 = kk*32 + g*8;
    half8 af[2];
#pragma unroll
    for (int ds = 0; ds < 2; ++ds) {
      const int d = (w*2 + ds)*16 + c16;
      const float4* gw = (const float4*)(g_w + (size_t)d*C_ + c0);
      float4 u0 = gw[0], u1 = gw[1];
      half8 a;
      a[0]=(_Float16)u0.x; a[1]=(_Float16)u0.y; a[2]=(_Float16)u0.z; a[3]=(_Float16)u0.w;
      a[4]=(_Float16)u1.x; a[5]=(_Float16)u1.y; a[6]=(_Float16)u1.z; a[7]=(_Float16)u1.w;
      af[ds] = a;
    }
#pragma unroll
    for (int ns = 0; ns < 8; ++ns) {
      const int nn = i*128 + ns*16 + c16;
      half8 bf;
#pragma unroll
      for (int j = 0; j < 8; ++j) bf[j] = (_Float16)xb[(size_t)(c0 + j)*N_ + nn];
      acc[0][ns] = __builtin_amdgcn_mfma_f32_16x16x32_f16(af[0], bf, acc[0][ns], 0, 0, 0);
      acc[1][ns] = __builtin_amdgcn_mfma_f32_16x16x32_f16(af[1], bf, acc[1][ns], 0, 0, 0);
    }
  }

#pragma unroll
  for (int ds = 0; ds < 2; ++ds) {
#pragma unroll
    for (int r = 0; r < 4; ++r) {
      const int d = (w*2 + ds)*16 + g*4 + r;
      const float gb = g_b[d];
#pragma unroll
      for (int s = 0; s < 4; ++s) {
        float v = fmaxf(acc[ds][s][r], acc[ds][s+4][r]);
        v = fmaxf(v, __shfl_xor(v, 1, 64));
        if ((l & 1) == 0) {
          const int m = i*32 + s*8 + (c16 >> 1);
          gpool[((size_t)b*D_ + d)*M_ + m] = (_Float16)(v + gb);
        }
      }
    }
  }
}

// ---------------------------------------------------------------------------
// P3: flash attention. 4 waves x 32 q-rows = 128 q/block. KVBLK=32 dbuf.
// global_load_lds staging (linear LDS + pre-swizzled source + swizzled reads),
// raw barriers + counted vmcnt(6). Ones-column PV gives softmax denom free.
// Defer-max (THR=8) kills per-chunk row reductions.
// ---------------------------------------------------------------------------
__global__ __launch_bounds__(256, 2) void attn_kernel(
    const float* __restrict__ x, const _Float16* __restrict__ phi,
    const _Float16* __restrict__ gpool, _Float16* __restrict__ y) {
  const int nt = blockIdx.x;           // 0..31
  const int b  = blockIdx.y;
  const int t  = threadIdx.x;
  const int w = t >> 6, l = t & 63, g = (l >> 4) & 3, c16 = l & 15;
  const int nw = nt*128 + w*32;

  __shared__ alignas(16) _Float16 phi_s[2][32*256];   // linear, swizzled content
  __shared__ alignas(16) _Float16 gp_s[2][128*32];    // linear, swizzled content
  __shared__ alignas(16) _Float16 p_s[4][32][40];     // per-wave P, pitch 80B

  // Q fragments: rows nw + rt*16 + c16, K=256 in 8 kk-steps
  half8 qf[2][8];
#pragma unroll
  for (int rt = 0; rt < 2; ++rt) {
    const int nq = nw + rt*16 + c16;
#pragma unroll
    for (int kk = 0; kk < 8; ++kk) {
      const int cb = kk*32 + g*8;
      half8 q;
#pragma unroll
      for (int j = 0; j < 8; ++j) q[j] = (_Float16)x[((size_t)b*C_ + cb + j)*N_ + nq];
      qf[rt][kk] = q;
    }
  }

  f32x4 yacc[2][8];
  f32x4 yext[2];
#pragma unroll
  for (int rt = 0; rt < 2; ++rt) {
    yext[rt] = (f32x4){0.f,0.f,0.f,0.f};
#pragma unroll
    for (int ds = 0; ds < 8; ++ds) yacc[rt][ds] = (f32x4){0.f,0.f,0.f,0.f};
  }
  float m_run[2][4];
#pragma unroll
  for (int rt = 0; rt < 2; ++rt)
#pragma unroll
    for (int r = 0; r < 4; ++r) m_run[rt][r] = -INFINITY;
  float mmin = -INFINITY;

  half8 e1;   // ones-column B-frag (col 0 = ones) for denom accumulation
#pragma unroll
  for (int j = 0; j < 8; ++j) e1[j] = (c16 == 0) ? (_Float16)1.0f : (_Float16)0.0f;

  const int l31 = l & 31, lhi = l >> 5;

  auto stage = [&](int buf, int ch2) {
    const int m0 = ch2 * 32;
    // phi chunk: 32 rows x 512B, 4 issues/wave, source pre-swizzled ^((m&3)<<4)
#pragma unroll
    for (int j = 0; j < 4; ++j) {
      const int mr = w*8 + j*2 + lhi;
      const char* src = (const char*)phi + ((size_t)(b*M_ + m0 + mr))*512 +
                        ((16*l31) ^ ((mr & 3) << 4));
      gl2lds16(src, (char*)&phi_s[buf][(w*8 + j*2)*C_]);
    }
    // gp chunk: 128 rows x 64B, 2 issues/wave, source pre-swizzled ^(((d>>1)&3)<<4)
#pragma unroll
    for (int j = 0; j < 2; ++j) {
      const int dr = w*32 + j*16 + (l >> 2);
      const char* src = (const char*)gpool + (((size_t)(b*D_ + dr))*M_ + m0)*2 +
                        ((16*(l & 3)) ^ (((dr >> 1) & 3) << 4));
      gl2lds16(src, (char*)&gp_s[buf][(w*32 + j*16)*32]);
    }
  };

  stage(0, 0);

  for (int ch = 0; ch < NCH; ++ch) {
    const int cur = ch & 1;
    if (ch + 1 < NCH) {
      stage(cur ^ 1, ch + 1);
      asm volatile("s_waitcnt vmcnt(6)" ::: "memory");   // cur's 6 landed; next's fly on
    } else {
      asm volatile("s_waitcnt vmcnt(0)" ::: "memory");
    }
    asm volatile("" ::: "memory");
    __builtin_amdgcn_s_barrier();
    asm volatile("" ::: "memory");

    // ---- QK^T: f[rt][mt], swizzled reads, one base + imm offsets
    f32x4 f[2][2];
    f[0][0] = (f32x4){0.f,0.f,0.f,0.f}; f[0][1] = (f32x4){0.f,0.f,0.f,0.f};
    f[1][0] = (f32x4){0.f,0.f,0.f,0.f}; f[1][1] = (f32x4){0.f,0.f,0.f,0.f};
    const char* pb = (const char*)&phi_s[cur][0] + c16*512 + ((g*16) ^ ((c16 & 3) << 4));
    __builtin_amdgcn_s_setprio(1);
#pragma unroll
    for (int kk = 0; kk < 8; ++kk) {
      half8 b0 = *(const half8*)(pb + kk*64);
      half8 b1 = *(const half8*)(pb + 8192 + kk*64);
      f[0][0] = __builtin_amdgcn_mfma_f32_16x16x32_f16(qf[0][kk], b0, f[0][0], 0, 0, 0);
      f[0][1] = __builtin_amdgcn_mfma_f32_16x16x32_f16(qf[0][kk], b1, f[0][1], 0, 0, 0);
      f[1][0] = __builtin_amdgcn_mfma_f32_16x16x32_f16(qf[1][kk], b0, f[1][0], 0, 0, 0);
      f[1][1] = __builtin_amdgcn_mfma_f32_16x16x32_f16(qf[1][kk], b1, f[1][1], 0, 0, 0);
    }
    __builtin_amdgcn_s_setprio(0);

    // ---- softmax: wave-max + defer-max test; no per-chunk row reductions
    float Wm = f[0][0][0];
#pragma unroll
    for (int rt = 0; rt < 2; ++rt)
#pragma unroll
      for (int mt = 0; mt < 2; ++mt)
#pragma unroll
        for (int r = 0; r < 4; ++r) Wm = fmaxf(Wm, f[rt][mt][r]);
    Wm = fmaxf(Wm, __shfl_xor(Wm, 1, 64));
    Wm = fmaxf(Wm, __shfl_xor(Wm, 2, 64));
    Wm = fmaxf(Wm, __shfl_xor(Wm, 4, 64));
    Wm = fmaxf(Wm, __shfl_xor(Wm, 8, 64));
    Wm = fmaxf(Wm, __shfl_xor(Wm, 16, 64));
    Wm = fmaxf(Wm, __shfl_xor(Wm, 32, 64));
    if (!(Wm <= mmin + 8.0f)) {   // slow path (rare): row maxes + rescale
      float nmmin = 1e30f;
#pragma unroll
      for (int rt = 0; rt < 2; ++rt)
#pragma unroll
        for (int r = 0; r < 4; ++r) {
          float cm = fmaxf(f[rt][0][r], f[rt][1][r]);
          cm = fmaxf(cm, __shfl_xor(cm, 1, 64));
          cm = fmaxf(cm, __shfl_xor(cm, 2, 64));
          cm = fmaxf(cm, __shfl_xor(cm, 4, 64));
          cm = fmaxf(cm, __shfl_xor(cm, 8, 64));
          const float mn = fmaxf(m_run[rt][r], cm);
          const float sc = __expf(m_run[rt][r] - mn);
#pragma unroll
          for (int ds = 0; ds < 8; ++ds) yacc[rt][ds][r] *= sc;
          yext[rt][r] *= sc;
          m_run[rt][r] = mn;
          nmmin = fminf(nmmin, mn);
        }
      nmmin = fminf(nmmin, __shfl_xor(nmmin, 16, 64));
      nmmin = fminf(nmmin, __shfl_xor(nmmin, 32, 64));
      mmin = nmmin;
    }
    // P = exp(f - m_run), store to per-wave p_s
#pragma unroll
    for (int rt = 0; rt < 2; ++rt)
#pragma unroll
      for (int r = 0; r < 4; ++r) {
        const float p0 = __expf(f[rt][0][r] - m_run[rt][r]);
        const float p1 = __expf(f[rt][1][r] - m_run[rt][r]);
        p_s[w][rt*16 + g*4 + r][c16]      = (_Float16)p0;
        p_s[w][rt*16 + g*4 + r][16 + c16] = (_Float16)p1;
      }
    asm volatile("s_waitcnt lgkmcnt(0)" ::: "memory");
    __builtin_amdgcn_sched_barrier(0);

    // ---- PV (+ ones column for denominator)
    half8 pa0 = *(const half8*)&p_s[w][c16][g*8];
    half8 pa1 = *(const half8*)&p_s[w][16 + c16][g*8];
    const char* gb = (const char*)&gp_s[cur][0] + c16*64 + ((g*16) ^ (((c16 >> 1) & 3) << 4));
    __builtin_amdgcn_s_setprio(1);
#pragma unroll
    for (int ds = 0; ds < 8; ++ds) {
      half8 bv = *(const half8*)(gb + ds*1024);
      yacc[0][ds] = __builtin_amdgcn_mfma_f32_16x16x32_f16(pa0, bv, yacc[0][ds], 0, 0, 0);
      yacc[1][ds] = __builtin_amdgcn_mfma_f32_16x16x32_f16(pa1, bv, yacc[1][ds], 0, 0, 0);
    }
    yext[0] = __builtin_amdgcn_mfma_f32_16x16x32_f16(pa0, e1, yext[0], 0, 0, 0);
    yext[1] = __builtin_amdgcn_mfma_f32_16x16x32_f16(pa1, e1, yext[1], 0, 0, 0);
    __builtin_amdgcn_s_setprio(0);

    asm volatile("" ::: "memory");
    __builtin_amdgcn_s_barrier();
    asm volatile("" ::: "memory");
  }

  // epilogue: broadcast denom over c16 lanes, normalize, write y fp16
#pragma unroll
  for (int rt = 0; rt < 2; ++rt)
#pragma unroll
    for (int r = 0; r < 4; ++r) {
      float ls = yext[rt][r];
      ls += __shfl_xor(ls, 1, 64);
      ls += __shfl_xor(ls, 2, 64);
      ls += __shfl_xor(ls, 4, 64);
      ls += __shfl_xor(ls, 8, 64);
      const float inv = 1.0f / ls;
      const int n = nw + rt*16 + g*4 + r;
      _Float16* yr = y + ((size_t)b*N_ + n)*D_ + c16;
#pragma unroll
      for (int ds = 0; ds < 8; ++ds) yr[ds*16] = (_Float16)(yacc[rt][ds][r] * inv);
    }
}

// ---------------------------------------------------------------------------
// P4a: W-conv (recompute from fp16 y) -> per-channel sum/sumsq via atomics
// ---------------------------------------------------------------------------
__global__ __launch_bounds__(256) void wconv_stats_kernel(
    const _Float16* __restrict__ y, const float* __restrict__ w_w,
    const float* __restrict__ w_b, float* __restrict__ bnsum,
    float* __restrict__ bnssq) {
  const int nt = blockIdx.x, b = blockIdx.y, t = threadIdx.x;
  const int w = t >> 6, l = t & 63, g = l >> 4, c16 = l & 15;
  const int n0 = nt*64;

  f32x4 acc[4][4];
#pragma unroll
  for (int a = 0; a < 4; ++a)
#pragma unroll
    for (int n = 0; n < 4; ++n) acc[a][n] = (f32x4){0.f,0.f,0.f,0.f};

#pragma unroll
  for (int kk = 0; kk < 4; ++kk) {
    const int d0 = kk*32 + g*8;
    half8 af[4];
#pragma unroll
    for (int cs = 0; cs < 4; ++cs) {
      const int c = w*64 + cs*16 + c16;
      const float4* p = (const float4*)(w_w + (size_t)c*D_ + d0);
      float4 u0 = p[0], u1 = p[1];
      half8 a;
      a[0]=(_Float16)u0.x; a[1]=(_Float16)u0.y; a[2]=(_Float16)u0.z; a[3]=(_Float16)u0.w;
      a[4]=(_Float16)u1.x; a[5]=(_Float16)u1.y; a[6]=(_Float16)u1.z; a[7]=(_Float16)u1.w;
      af[cs] = a;
    }
#pragma unroll
    for (int ns = 0; ns < 4; ++ns) {
      const int nn = n0 + ns*16 + c16;
      half8 bf = *(const half8*)&y[((size_t)b*N_ + nn)*D_ + d0];
#pragma unroll
      for (int cs = 0; cs < 4; ++cs)
        acc[cs][ns] = __builtin_amdgcn_mfma_f32_16x16x32_f16(af[cs], bf, acc[cs][ns], 0, 0, 0);
    }
  }

#pragma unroll
  for (int cs = 0; cs < 4; ++cs) {
#pragma unroll
    for (int r = 0; r < 4; ++r) {
      const int c = w*64 + cs*16 + g*4 + r;
      const float wb = w_b[c];
      float s = 0.f, q = 0.f;
#pragma unroll
      for (int ns = 0; ns < 4; ++ns) {
        const float v = acc[cs][ns][r] + wb;
        s += v; q += v*v;
      }
      s += __shfl_xor(s, 1, 64); s += __shfl_xor(s, 2, 64);
      s += __shfl_xor(s, 4, 64); s += __shfl_xor(s, 8, 64);
      q += __shfl_xor(q, 1, 64); q += __shfl_xor(q, 2, 64);
      q += __shfl_xor(q, 4, 64); q += __shfl_xor(q, 8, 64);
      if (c16 == 0) { atomicAdd(&bnsum[c], s); atomicAdd(&bnssq[c], q); }
    }
  }
}

// ---------------------------------------------------------------------------
// P4b: W-conv recompute (fp16 y) + BatchNorm + residual -> out[b][c][n] f32
// ---------------------------------------------------------------------------
__global__ __launch_bounds__(256) void wconv_bn_kernel(
    const _Float16* __restrict__ y, const float* __restrict__ w_w,
    const float* __restrict__ w_b, const float* __restrict__ bnsum,
    const float* __restrict__ bnssq, const float* __restrict__ gamma,
    const float* __restrict__ beta, const float* __restrict__ x,
    float* __restrict__ out) {
  const int nt = blockIdx.x, b = blockIdx.y, t = threadIdx.x;
  const int w = t >> 6, l = t & 63, g = l >> 4, c16 = l & 15;
  const int n0 = nt*64;

  f32x4 acc[4][4];
#pragma unroll
  for (int a = 0; a < 4; ++a)
#pragma unroll
    for (int n = 0; n < 4; ++n) acc[a][n] = (f32x4){0.f,0.f,0.f,0.f};

#pragma unroll
  for (int kk = 0; kk < 4; ++kk) {
    const int d0 = kk*32 + g*8;
    half8 af[4];
#pragma unroll
    for (int cs = 0; cs < 4; ++cs) {
      const int c = w*64 + cs*16 + c16;
      const float4* p = (const float4*)(w_w + (size_t)c*D_ + d0);
      float4 u0 = p[0], u1 = p[1];
      half8 a;
      a[0]=(_Float16)u0.x; a[1]=(_Float16)u0.y; a[2]=(_Float16)u0.z; a[3]=(_Float16)u0.w;
      a[4]=(_Float16)u1.x; a[5]=(_Float16)u1.y; a[6]=(_Float16)u1.z; a[7]=(_Float16)u1.w;
      af[cs] = a;
    }
#pragma unroll
    for (int ns = 0; ns < 4; ++ns) {
      const int nn = n0 + ns*16 + c16;
      half8 bf = *(const half8*)&y[((size_t)b*N_ + nn)*D_ + d0];
#pragma unroll
      for (int cs = 0; cs < 4; ++cs)
        acc[cs][ns] = __builtin_amdgcn_mfma_f32_16x16x32_f16(af[cs], bf, acc[cs][ns], 0, 0, 0);
    }
  }

  const float inv_cnt = 1.0f / (float)((size_t)B_ * N_);
#pragma unroll
  for (int cs = 0; cs < 4; ++cs) {
#pragma unroll
    for (int r = 0; r < 4; ++r) {
      const int c = w*64 + cs*16 + g*4 + r;
      const float wb  = w_b[c];
      const float mean = bnsum[c] * inv_cnt;
      const float var  = bnssq[c] * inv_cnt - mean*mean;
      const float istd = rsqrtf(var + 1e-5f);
      const float ga = gamma[c], be = beta[c];
#pragma unroll
      for (int ns = 0; ns < 4; ++ns) {
        const int n = n0 + ns*16 + c16;
        const size_t idx = ((size_t)b*C_ + c)*N_ + n;
        const float v = acc[cs][ns][r] + wb;
        out[idx] = (v - mean)*istd*ga + be + x[idx];
      }
    }
  }
}

// ---------------------------------------------------------------------------
extern "C" void kernel_launch(void* const* d_in, const int* in_sizes, int n_in,
                              void* d_out, int out_size, void* d_ws, size_t ws_size,
                              hipStream_t stream) {
  const float* x     = (const float*)d_in[0];
  const float* g_w   = (const float*)d_in[1];
  const float* g_b   = (const float*)d_in[2];
  const float* w_w   = (const float*)d_in[3];
  const float* w_b   = (const float*)d_in[4];
  const float* gamma = (const float*)d_in[5];
  const float* beta  = (const float*)d_in[6];
  float* out = (float*)d_out;

  char* ws = (char*)d_ws;
  _Float16* phi   = (_Float16*)(ws + WS_PHI);
  _Float16* gpool = (_Float16*)(ws + WS_GPOOL);
  _Float16* yb    = (_Float16*)(ws + WS_Y);
  float*    bnsum = (float*)(ws + WS_BNSUM);
  float*    bnssq = (float*)(ws + WS_BNSSQ);

  pool_phi_kernel<<<dim3(32, 16), 256, 0, stream>>>(x, phi);
  gconv_pool_kernel<<<dim3(32, 16), 256, 0, stream>>>(x, g_w, g_b, gpool);
  hipMemsetAsync(bnsum, 0, 2*C_*sizeof(float), stream);
  attn_kernel<<<dim3(32, 16), 256, 0, stream>>>(x, phi, gpool, yb);
  wconv_stats_kernel<<<dim3(64, 16), 256, 0, stream>>>(yb, w_w, w_b, bnsum, bnssq);
  wconv_bn_kernel<<<dim3(64, 16), 256, 0, stream>>>(yb, w_w, w_b, bnsum, bnssq, gamma, beta, x, out);
}

// Round 3
// 266.490 us; speedup vs baseline: 1.5899x; 1.4027x over previous
//
#include <hip/hip_runtime.h>
#include <hip/hip_bf16.h>

typedef _Float16 half8 __attribute__((ext_vector_type(8)));
typedef float f32x4 __attribute__((ext_vector_type(4)));

#define B_ 16
#define C_ 256
#define D_ 128
#define H_ 64
#define W_ 64
#define N_ 4096   // H*W
#define M_ 1024   // (H/2)*(W/2)
#define NCH 32    // M/32 key chunks

// workspace layout (bytes)
static constexpr size_t WS_PHI   = 0;                                  // fp16 [B][M][C]   8 MB
static constexpr size_t WS_GPOOL = WS_PHI   + (size_t)B_*M_*C_*2;      // fp16 [B][D][M]   4 MB
static constexpr size_t WS_Y     = WS_GPOOL + (size_t)B_*D_*M_*2;      // fp16 [B][N][D]  16 MB
static constexpr size_t WS_BNSUM = WS_Y     + (size_t)B_*N_*D_*2;      // f32  [C]
static constexpr size_t WS_BNSSQ = WS_BNSUM + (size_t)C_*4;            // f32  [C]
static constexpr size_t WS_PSUM  = WS_BNSSQ + (size_t)C_*4;            // f32  [256][256]
static constexpr size_t WS_PSSQ  = WS_PSUM  + (size_t)256*256*4;       // f32  [256][256]

typedef __attribute__((address_space(3))) void lds_vt;
typedef const __attribute__((address_space(1))) void gbl_vt;

__device__ __forceinline__ void gl2lds16(const void* g, void* s) {
  __builtin_amdgcn_global_load_lds((gbl_vt*)g, (lds_vt*)s, 16, 0, 0);
}

// ---------------------------------------------------------------------------
// P1+P2 fused: one pass over x producing
//   phi[b][m][c]   = fp16(maxpool2x2(x))          (pool of the B-frag values)
//   gpool[b][d][m] = fp16(maxpool2x2(g_w *. x) + g_b)
// grid (32 row-pairs, 16 batches), 256 threads.
// ---------------------------------------------------------------------------
__global__ __launch_bounds__(256) void fused_pre_kernel(
    const float* __restrict__ x, const float* __restrict__ g_w,
    const float* __restrict__ g_b, _Float16* __restrict__ phi,
    _Float16* __restrict__ gpool) {
  const int i = blockIdx.x;            // image row-pair (rows 2i, 2i+1)
  const int b = blockIdx.y;
  const int t = threadIdx.x;
  const int w = t >> 6, l = t & 63, g = l >> 4, c16 = l & 15;
  const float* xb = x + (size_t)b*C_*N_;

  f32x4 acc[2][8];
#pragma unroll
  for (int a = 0; a < 2; ++a)
#pragma unroll
    for (int n = 0; n < 8; ++n) acc[a][n] = (f32x4){0.f,0.f,0.f,0.f};

  for (int kk = 0; kk < 8; ++kk) {
    const int c0 = kk*32 + g*8;
    half8 af[2];
#pragma unroll
    for (int ds = 0; ds < 2; ++ds) {
      const int d = (w*2 + ds)*16 + c16;
      const float4* gw = (const float4*)(g_w + (size_t)d*C_ + c0);
      float4 u0 = gw[0], u1 = gw[1];
      half8 a;
      a[0]=(_Float16)u0.x; a[1]=(_Float16)u0.y; a[2]=(_Float16)u0.z; a[3]=(_Float16)u0.w;
      a[4]=(_Float16)u1.x; a[5]=(_Float16)u1.y; a[6]=(_Float16)u1.z; a[7]=(_Float16)u1.w;
      af[ds] = a;
    }
    // B-fragments (x values), kept for both MFMA and phi pooling
    half8 bf[8];
#pragma unroll
    for (int ns = 0; ns < 8; ++ns) {
      const int nn = i*128 + ns*16 + c16;
      half8 v;
#pragma unroll
      for (int j = 0; j < 8; ++j) v[j] = (_Float16)xb[(size_t)(c0 + j)*N_ + nn];
      bf[ns] = v;
    }
    // phi: 2x2 pool of x. vertical = ns vs ns+4, horizontal = lane pair.
#pragma unroll
    for (int j = 0; j < 8; ++j) {
#pragma unroll
      for (int s = 0; s < 4; ++s) {
        float v = fmaxf((float)bf[s][j], (float)bf[s+4][j]);
        v = fmaxf(v, __shfl_xor(v, 1, 64));
        if (!(l & 1)) {
          const int m = i*32 + s*8 + (c16 >> 1);
          phi[((size_t)b*M_ + m)*C_ + c0 + j] = (_Float16)v;
        }
      }
    }
#pragma unroll
    for (int ns = 0; ns < 8; ++ns) {
      acc[0][ns] = __builtin_amdgcn_mfma_f32_16x16x32_f16(af[0], bf[ns], acc[0][ns], 0, 0, 0);
      acc[1][ns] = __builtin_amdgcn_mfma_f32_16x16x32_f16(af[1], bf[ns], acc[1][ns], 0, 0, 0);
    }
  }

#pragma unroll
  for (int ds = 0; ds < 2; ++ds) {
#pragma unroll
    for (int r = 0; r < 4; ++r) {
      const int d = (w*2 + ds)*16 + g*4 + r;
      const float gb = g_b[d];
#pragma unroll
      for (int s = 0; s < 4; ++s) {
        float v = fmaxf(acc[ds][s][r], acc[ds][s+4][r]);
        v = fmaxf(v, __shfl_xor(v, 1, 64));
        if ((l & 1) == 0) {
          const int m = i*32 + s*8 + (c16 >> 1);
          gpool[((size_t)b*D_ + d)*M_ + m] = (_Float16)(v + gb);
        }
      }
    }
  }
}

// ---------------------------------------------------------------------------
// P3: flash attention (unchanged from round 2 — passed, ~<90us)
// ---------------------------------------------------------------------------
__global__ __launch_bounds__(256, 2) void attn_kernel(
    const float* __restrict__ x, const _Float16* __restrict__ phi,
    const _Float16* __restrict__ gpool, _Float16* __restrict__ y) {
  const int nt = blockIdx.x;           // 0..31
  const int b  = blockIdx.y;
  const int t  = threadIdx.x;
  const int w = t >> 6, l = t & 63, g = (l >> 4) & 3, c16 = l & 15;
  const int nw = nt*128 + w*32;

  __shared__ alignas(16) _Float16 phi_s[2][32*256];   // linear, swizzled content
  __shared__ alignas(16) _Float16 gp_s[2][128*32];    // linear, swizzled content
  __shared__ alignas(16) _Float16 p_s[4][32][40];     // per-wave P, pitch 80B

  half8 qf[2][8];
#pragma unroll
  for (int rt = 0; rt < 2; ++rt) {
    const int nq = nw + rt*16 + c16;
#pragma unroll
    for (int kk = 0; kk < 8; ++kk) {
      const int cb = kk*32 + g*8;
      half8 q;
#pragma unroll
      for (int j = 0; j < 8; ++j) q[j] = (_Float16)x[((size_t)b*C_ + cb + j)*N_ + nq];
      qf[rt][kk] = q;
    }
  }

  f32x4 yacc[2][8];
  f32x4 yext[2];
#pragma unroll
  for (int rt = 0; rt < 2; ++rt) {
    yext[rt] = (f32x4){0.f,0.f,0.f,0.f};
#pragma unroll
    for (int ds = 0; ds < 8; ++ds) yacc[rt][ds] = (f32x4){0.f,0.f,0.f,0.f};
  }
  float m_run[2][4];
#pragma unroll
  for (int rt = 0; rt < 2; ++rt)
#pragma unroll
    for (int r = 0; r < 4; ++r) m_run[rt][r] = -INFINITY;
  float mmin = -INFINITY;

  half8 e1;
#pragma unroll
  for (int j = 0; j < 8; ++j) e1[j] = (c16 == 0) ? (_Float16)1.0f : (_Float16)0.0f;

  const int l31 = l & 31, lhi = l >> 5;

  auto stage = [&](int buf, int ch2) {
    const int m0 = ch2 * 32;
#pragma unroll
    for (int j = 0; j < 4; ++j) {
      const int mr = w*8 + j*2 + lhi;
      const char* src = (const char*)phi + ((size_t)(b*M_ + m0 + mr))*512 +
                        ((16*l31) ^ ((mr & 3) << 4));
      gl2lds16(src, (char*)&phi_s[buf][(w*8 + j*2)*C_]);
    }
#pragma unroll
    for (int j = 0; j < 2; ++j) {
      const int dr = w*32 + j*16 + (l >> 2);
      const char* src = (const char*)gpool + (((size_t)(b*D_ + dr))*M_ + m0)*2 +
                        ((16*(l & 3)) ^ (((dr >> 1) & 3) << 4));
      gl2lds16(src, (char*)&gp_s[buf][(w*32 + j*16)*32]);
    }
  };

  stage(0, 0);

  for (int ch = 0; ch < NCH; ++ch) {
    const int cur = ch & 1;
    if (ch + 1 < NCH) {
      stage(cur ^ 1, ch + 1);
      asm volatile("s_waitcnt vmcnt(6)" ::: "memory");
    } else {
      asm volatile("s_waitcnt vmcnt(0)" ::: "memory");
    }
    asm volatile("" ::: "memory");
    __builtin_amdgcn_s_barrier();
    asm volatile("" ::: "memory");

    f32x4 f[2][2];
    f[0][0] = (f32x4){0.f,0.f,0.f,0.f}; f[0][1] = (f32x4){0.f,0.f,0.f,0.f};
    f[1][0] = (f32x4){0.f,0.f,0.f,0.f}; f[1][1] = (f32x4){0.f,0.f,0.f,0.f};
    const char* pb = (const char*)&phi_s[cur][0] + c16*512 + ((g*16) ^ ((c16 & 3) << 4));
    __builtin_amdgcn_s_setprio(1);
#pragma unroll
    for (int kk = 0; kk < 8; ++kk) {
      half8 b0 = *(const half8*)(pb + kk*64);
      half8 b1 = *(const half8*)(pb + 8192 + kk*64);
      f[0][0] = __builtin_amdgcn_mfma_f32_16x16x32_f16(qf[0][kk], b0, f[0][0], 0, 0, 0);
      f[0][1] = __builtin_amdgcn_mfma_f32_16x16x32_f16(qf[0][kk], b1, f[0][1], 0, 0, 0);
      f[1][0] = __builtin_amdgcn_mfma_f32_16x16x32_f16(qf[1][kk], b0, f[1][0], 0, 0, 0);
      f[1][1] = __builtin_amdgcn_mfma_f32_16x16x32_f16(qf[1][kk], b1, f[1][1], 0, 0, 0);
    }
    __builtin_amdgcn_s_setprio(0);

    float Wm = f[0][0][0];
#pragma unroll
    for (int rt = 0; rt < 2; ++rt)
#pragma unroll
      for (int mt = 0; mt < 2; ++mt)
#pragma unroll
        for (int r = 0; r < 4; ++r) Wm = fmaxf(Wm, f[rt][mt][r]);
    Wm = fmaxf(Wm, __shfl_xor(Wm, 1, 64));
    Wm = fmaxf(Wm, __shfl_xor(Wm, 2, 64));
    Wm = fmaxf(Wm, __shfl_xor(Wm, 4, 64));
    Wm = fmaxf(Wm, __shfl_xor(Wm, 8, 64));
    Wm = fmaxf(Wm, __shfl_xor(Wm, 16, 64));
    Wm = fmaxf(Wm, __shfl_xor(Wm, 32, 64));
    if (!(Wm <= mmin + 8.0f)) {
      float nmmin = 1e30f;
#pragma unroll
      for (int rt = 0; rt < 2; ++rt)
#pragma unroll
        for (int r = 0; r < 4; ++r) {
          float cm = fmaxf(f[rt][0][r], f[rt][1][r]);
          cm = fmaxf(cm, __shfl_xor(cm, 1, 64));
          cm = fmaxf(cm, __shfl_xor(cm, 2, 64));
          cm = fmaxf(cm, __shfl_xor(cm, 4, 64));
          cm = fmaxf(cm, __shfl_xor(cm, 8, 64));
          const float mn = fmaxf(m_run[rt][r], cm);
          const float sc = __expf(m_run[rt][r] - mn);
#pragma unroll
          for (int ds = 0; ds < 8; ++ds) yacc[rt][ds][r] *= sc;
          yext[rt][r] *= sc;
          m_run[rt][r] = mn;
          nmmin = fminf(nmmin, mn);
        }
      nmmin = fminf(nmmin, __shfl_xor(nmmin, 16, 64));
      nmmin = fminf(nmmin, __shfl_xor(nmmin, 32, 64));
      mmin = nmmin;
    }
#pragma unroll
    for (int rt = 0; rt < 2; ++rt)
#pragma unroll
      for (int r = 0; r < 4; ++r) {
        const float p0 = __expf(f[rt][0][r] - m_run[rt][r]);
        const float p1 = __expf(f[rt][1][r] - m_run[rt][r]);
        p_s[w][rt*16 + g*4 + r][c16]      = (_Float16)p0;
        p_s[w][rt*16 + g*4 + r][16 + c16] = (_Float16)p1;
      }
    asm volatile("s_waitcnt lgkmcnt(0)" ::: "memory");
    __builtin_amdgcn_sched_barrier(0);

    half8 pa0 = *(const half8*)&p_s[w][c16][g*8];
    half8 pa1 = *(const half8*)&p_s[w][16 + c16][g*8];
    const char* gb = (const char*)&gp_s[cur][0] + c16*64 + ((g*16) ^ (((c16 >> 1) & 3) << 4));
    __builtin_amdgcn_s_setprio(1);
#pragma unroll
    for (int ds = 0; ds < 8; ++ds) {
      half8 bv = *(const half8*)(gb + ds*1024);
      yacc[0][ds] = __builtin_amdgcn_mfma_f32_16x16x32_f16(pa0, bv, yacc[0][ds], 0, 0, 0);
      yacc[1][ds] = __builtin_amdgcn_mfma_f32_16x16x32_f16(pa1, bv, yacc[1][ds], 0, 0, 0);
    }
    yext[0] = __builtin_amdgcn_mfma_f32_16x16x32_f16(pa0, e1, yext[0], 0, 0, 0);
    yext[1] = __builtin_amdgcn_mfma_f32_16x16x32_f16(pa1, e1, yext[1], 0, 0, 0);
    __builtin_amdgcn_s_setprio(0);

    asm volatile("" ::: "memory");
    __builtin_amdgcn_s_barrier();
    asm volatile("" ::: "memory");
  }

#pragma unroll
  for (int rt = 0; rt < 2; ++rt)
#pragma unroll
    for (int r = 0; r < 4; ++r) {
      float ls = yext[rt][r];
      ls += __shfl_xor(ls, 1, 64);
      ls += __shfl_xor(ls, 2, 64);
      ls += __shfl_xor(ls, 4, 64);
      ls += __shfl_xor(ls, 8, 64);
      const float inv = 1.0f / ls;
      const int n = nw + rt*16 + g*4 + r;
      _Float16* yr = y + ((size_t)b*N_ + n)*D_ + c16;
#pragma unroll
      for (int ds = 0; ds < 8; ++ds) yr[ds*16] = (_Float16)(yacc[rt][ds][r] * inv);
    }
}

// ---------------------------------------------------------------------------
// P4a: W-conv recompute -> per-(block,channel) partial sum/sumsq. NO atomics.
// grid (16 n-tiles of 256 rows, 16 b) = 256 blocks; partial[blk=b*16+nt][c].
// ---------------------------------------------------------------------------
__global__ __launch_bounds__(256) void stats_partial_kernel(
    const _Float16* __restrict__ y, const float* __restrict__ w_w,
    const float* __restrict__ w_b, float* __restrict__ psum,
    float* __restrict__ pssq) {
  const int nt = blockIdx.x, b = blockIdx.y, t = threadIdx.x;
  const int w = t >> 6, l = t & 63, g = l >> 4, c16 = l & 15;

  float s_acc[4][4], q_acc[4][4], wb_r[4][4];
#pragma unroll
  for (int cs = 0; cs < 4; ++cs)
#pragma unroll
    for (int r = 0; r < 4; ++r) {
      s_acc[cs][r] = 0.f; q_acc[cs][r] = 0.f;
      wb_r[cs][r] = w_b[w*64 + cs*16 + g*4 + r];
    }

  for (int nb = 0; nb < 4; ++nb) {
    const int n0 = nt*256 + nb*64;
    f32x4 acc[4][4];
#pragma unroll
    for (int a = 0; a < 4; ++a)
#pragma unroll
      for (int n = 0; n < 4; ++n) acc[a][n] = (f32x4){0.f,0.f,0.f,0.f};

#pragma unroll
    for (int kk = 0; kk < 4; ++kk) {
      const int d0 = kk*32 + g*8;
      half8 af[4];
#pragma unroll
      for (int cs = 0; cs < 4; ++cs) {
        const int c = w*64 + cs*16 + c16;
        const float4* p = (const float4*)(w_w + (size_t)c*D_ + d0);
        float4 u0 = p[0], u1 = p[1];
        half8 a;
        a[0]=(_Float16)u0.x; a[1]=(_Float16)u0.y; a[2]=(_Float16)u0.z; a[3]=(_Float16)u0.w;
        a[4]=(_Float16)u1.x; a[5]=(_Float16)u1.y; a[6]=(_Float16)u1.z; a[7]=(_Float16)u1.w;
        af[cs] = a;
      }
#pragma unroll
      for (int ns = 0; ns < 4; ++ns) {
        const int nn = n0 + ns*16 + c16;
        half8 bf = *(const half8*)&y[((size_t)b*N_ + nn)*D_ + d0];
#pragma unroll
        for (int cs = 0; cs < 4; ++cs)
          acc[cs][ns] = __builtin_amdgcn_mfma_f32_16x16x32_f16(af[cs], bf, acc[cs][ns], 0, 0, 0);
      }
    }
#pragma unroll
    for (int cs = 0; cs < 4; ++cs)
#pragma unroll
      for (int r = 0; r < 4; ++r) {
        const float wb = wb_r[cs][r];
#pragma unroll
        for (int ns = 0; ns < 4; ++ns) {
          const float v = acc[cs][ns][r] + wb;
          s_acc[cs][r] += v; q_acc[cs][r] += v*v;
        }
      }
  }

  const int blk = b*16 + nt;
#pragma unroll
  for (int cs = 0; cs < 4; ++cs)
#pragma unroll
    for (int r = 0; r < 4; ++r) {
      float s = s_acc[cs][r], q = q_acc[cs][r];
      s += __shfl_xor(s, 1, 64); s += __shfl_xor(s, 2, 64);
      s += __shfl_xor(s, 4, 64); s += __shfl_xor(s, 8, 64);
      q += __shfl_xor(q, 1, 64); q += __shfl_xor(q, 2, 64);
      q += __shfl_xor(q, 4, 64); q += __shfl_xor(q, 8, 64);
      if (c16 == 0) {
        const int c = w*64 + cs*16 + g*4 + r;
        psum[blk*C_ + c] = s;
        pssq[blk*C_ + c] = q;
      }
    }
}

// ---------------------------------------------------------------------------
// P4a2: reduce 256 partials -> bnsum/bnssq. grid 8 blocks x 256t.
// ---------------------------------------------------------------------------
__global__ __launch_bounds__(256) void stats_reduce_kernel(
    const float* __restrict__ psum, const float* __restrict__ pssq,
    float* __restrict__ bnsum, float* __restrict__ bnssq) {
  const int t = threadIdx.x;
  const int ci = t & 31, bi = t >> 5;           // bi 0..7
  const int c = blockIdx.x*32 + ci;
  float s = 0.f, q = 0.f;
  for (int k = 0; k < 32; ++k) {
    const int row = bi + k*8;
    s += psum[row*C_ + c];
    q += pssq[row*C_ + c];
  }
  __shared__ float rs[8][32], rq[8][32];
  rs[bi][ci] = s; rq[bi][ci] = q;
  __syncthreads();
  if (bi == 0) {
    float S = 0.f, Q = 0.f;
#pragma unroll
    for (int k2 = 0; k2 < 8; ++k2) { S += rs[k2][ci]; Q += rq[k2][ci]; }
    bnsum[c] = S; bnssq[c] = Q;
  }
}

// ---------------------------------------------------------------------------
// P4b: W-conv recompute (fp16 y) + BatchNorm + residual -> out[b][c][n] f32
// ---------------------------------------------------------------------------
__global__ __launch_bounds__(256) void wconv_bn_kernel(
    const _Float16* __restrict__ y, const float* __restrict__ w_w,
    const float* __restrict__ w_b, const float* __restrict__ bnsum,
    const float* __restrict__ bnssq, const float* __restrict__ gamma,
    const float* __restrict__ beta, const float* __restrict__ x,
    float* __restrict__ out) {
  const int nt = blockIdx.x, b = blockIdx.y, t = threadIdx.x;
  const int w = t >> 6, l = t & 63, g = l >> 4, c16 = l & 15;
  const int n0 = nt*64;

  f32x4 acc[4][4];
#pragma unroll
  for (int a = 0; a < 4; ++a)
#pragma unroll
    for (int n = 0; n < 4; ++n) acc[a][n] = (f32x4){0.f,0.f,0.f,0.f};

#pragma unroll
  for (int kk = 0; kk < 4; ++kk) {
    const int d0 = kk*32 + g*8;
    half8 af[4];
#pragma unroll
    for (int cs = 0; cs < 4; ++cs) {
      const int c = w*64 + cs*16 + c16;
      const float4* p = (const float4*)(w_w + (size_t)c*D_ + d0);
      float4 u0 = p[0], u1 = p[1];
      half8 a;
      a[0]=(_Float16)u0.x; a[1]=(_Float16)u0.y; a[2]=(_Float16)u0.z; a[3]=(_Float16)u0.w;
      a[4]=(_Float16)u1.x; a[5]=(_Float16)u1.y; a[6]=(_Float16)u1.z; a[7]=(_Float16)u1.w;
      af[cs] = a;
    }
#pragma unroll
    for (int ns = 0; ns < 4; ++ns) {
      const int nn = n0 + ns*16 + c16;
      half8 bf = *(const half8*)&y[((size_t)b*N_ + nn)*D_ + d0];
#pragma unroll
      for (int cs = 0; cs < 4; ++cs)
        acc[cs][ns] = __builtin_amdgcn_mfma_f32_16x16x32_f16(af[cs], bf, acc[cs][ns], 0, 0, 0);
    }
  }

  const float inv_cnt = 1.0f / (float)((size_t)B_ * N_);
#pragma unroll
  for (int cs = 0; cs < 4; ++cs) {
#pragma unroll
    for (int r = 0; r < 4; ++r) {
      const int c = w*64 + cs*16 + g*4 + r;
      const float wb  = w_b[c];
      const float mean = bnsum[c] * inv_cnt;
      const float var  = bnssq[c] * inv_cnt - mean*mean;
      const float istd = rsqrtf(var + 1e-5f);
      const float ga = gamma[c], be = beta[c];
#pragma unroll
      for (int ns = 0; ns < 4; ++ns) {
        const int n = n0 + ns*16 + c16;
        const size_t idx = ((size_t)b*C_ + c)*N_ + n;
        const float v = acc[cs][ns][r] + wb;
        out[idx] = (v - mean)*istd*ga + be + x[idx];
      }
    }
  }
}

// ---------------------------------------------------------------------------
extern "C" void kernel_launch(void* const* d_in, const int* in_sizes, int n_in,
                              void* d_out, int out_size, void* d_ws, size_t ws_size,
                              hipStream_t stream) {
  const float* x     = (const float*)d_in[0];
  const float* g_w   = (const float*)d_in[1];
  const float* g_b   = (const float*)d_in[2];
  const float* w_w   = (const float*)d_in[3];
  const float* w_b   = (const float*)d_in[4];
  const float* gamma = (const float*)d_in[5];
  const float* beta  = (const float*)d_in[6];
  float* out = (float*)d_out;

  char* ws = (char*)d_ws;
  _Float16* phi   = (_Float16*)(ws + WS_PHI);
  _Float16* gpool = (_Float16*)(ws + WS_GPOOL);
  _Float16* yb    = (_Float16*)(ws + WS_Y);
  float*    bnsum = (float*)(ws + WS_BNSUM);
  float*    bnssq = (float*)(ws + WS_BNSSQ);
  float*    psum  = (float*)(ws + WS_PSUM);
  float*    pssq  = (float*)(ws + WS_PSSQ);

  fused_pre_kernel<<<dim3(32, 16), 256, 0, stream>>>(x, g_w, g_b, phi, gpool);
  attn_kernel<<<dim3(32, 16), 256, 0, stream>>>(x, phi, gpool, yb);
  stats_partial_kernel<<<dim3(16, 16), 256, 0, stream>>>(yb, w_w, w_b, psum, pssq);
  stats_reduce_kernel<<<8, 256, 0, stream>>>(psum, pssq, bnsum, bnssq);
  wconv_bn_kernel<<<dim3(64, 16), 256, 0, stream>>>(yb, w_w, w_b, bnsum, bnssq, gamma, beta, x, out);
}

// Round 5
// 228.813 us; speedup vs baseline: 1.8517x; 1.1647x over previous
//
#include <hip/hip_runtime.h>
#include <hip/hip_bf16.h>

typedef _Float16 half8 __attribute__((ext_vector_type(8)));
typedef float f32x4 __attribute__((ext_vector_type(4)));
typedef unsigned uint4e __attribute__((ext_vector_type(4)));

#define B_ 16
#define C_ 256
#define D_ 128
#define H_ 64
#define W_ 64
#define N_ 4096   // H*W
#define M_ 1024   // (H/2)*(W/2)
#define NCH 32    // M/32 key chunks

// workspace layout (bytes)
static constexpr size_t WS_PHI   = 0;                                  // fp16 [B][M][C]   8 MB
static constexpr size_t WS_GPOOL = WS_PHI   + (size_t)B_*M_*C_*2;      // fp16 [B][D][M]   4 MB
static constexpr size_t WS_Y     = WS_GPOOL + (size_t)B_*D_*M_*2;      // fp16 [B][N][D]  16 MB
static constexpr size_t WS_BNSUM = WS_Y     + (size_t)B_*N_*D_*2;      // f32  [C]
static constexpr size_t WS_BNSSQ = WS_BNSUM + (size_t)C_*4;            // f32  [C]
static constexpr size_t WS_PSUM  = WS_BNSSQ + (size_t)C_*4;            // f32  [256][256]
static constexpr size_t WS_PSSQ  = WS_PSUM  + (size_t)256*256*4;       // f32  [256][256]
static constexpr size_t WS_GW16  = WS_PSSQ  + (size_t)256*256*4;       // fp16 [D][C] 64KB
static constexpr size_t WS_WW16  = WS_GW16  + (size_t)D_*C_*2;         // fp16 [C][D] 64KB

typedef __attribute__((address_space(3))) void lds_vt;
typedef const __attribute__((address_space(1))) void gbl_vt;

__device__ __forceinline__ void gl2lds16(const void* g, void* s) {
  __builtin_amdgcn_global_load_lds((gbl_vt*)g, (lds_vt*)s, 16, 0, 0);
}

__device__ __forceinline__ unsigned pkrtz(float a, float b) {
  auto v = __builtin_amdgcn_cvt_pkrtz(a, b);   // __fp16 ext_vector(2)
  return __builtin_bit_cast(unsigned, v);
}

// ---------------------------------------------------------------------------
// P0: convert weights to fp16 once. gw16[d][c], ww16[c][d].
// ---------------------------------------------------------------------------
__global__ __launch_bounds__(256) void conv16_kernel(
    const float* __restrict__ gw, const float* __restrict__ ww,
    _Float16* __restrict__ gw16, _Float16* __restrict__ ww16) {
  const int i = blockIdx.x*256 + threadIdx.x;   // 0..32767
  gw16[i] = (_Float16)gw[i];
  ww16[i] = (_Float16)ww[i];
}

// ---------------------------------------------------------------------------
// P1+P2 fused: one pass over x producing
//   phi[b][m][c]   = fp16(maxpool2x2(x))
//   gpool[b][d][m] = fp16(maxpool2x2(g_w *. x) + g_b)
// Waves partition n; each wave covers all d. grid (32 row-pairs, 16 batches).
// ---------------------------------------------------------------------------
__global__ __launch_bounds__(256) void fused_pre_kernel(
    const float* __restrict__ x, const _Float16* __restrict__ gw16,
    const float* __restrict__ g_b, _Float16* __restrict__ phi,
    _Float16* __restrict__ gpool) {
  const int i = blockIdx.x;            // image row-pair (rows 2i, 2i+1)
  const int b = blockIdx.y;
  const int t = threadIdx.x;
  const int w = t >> 6, l = t & 63, gq = l >> 4, c16 = l & 15;
  const float* xb = x + (size_t)b*C_*N_;

  f32x4 acc[8][2];
#pragma unroll
  for (int ds = 0; ds < 8; ++ds) {
    acc[ds][0] = (f32x4){0.f,0.f,0.f,0.f};
    acc[ds][1] = (f32x4){0.f,0.f,0.f,0.f};
  }

  const int n0 = i*128 + w*16 + c16;   // ns = w
  const int mrow = i*32 + w*8 + (c16 >> 1);

  for (int kk = 0; kk < 8; ++kk) {
    const int c0 = kk*32 + gq*8;
    half8 bf0, bf1;
#pragma unroll
    for (int j = 0; j < 8; ++j) {
      bf0[j] = (_Float16)xb[(size_t)(c0 + j)*N_ + n0];
      bf1[j] = (_Float16)xb[(size_t)(c0 + j)*N_ + n0 + 64];
    }
    // phi: vertical pool (bf0 vs bf1) + horizontal lane-pair pool
    half8 pk_;
#pragma unroll
    for (int j = 0; j < 8; ++j) {
      float v = fmaxf((float)bf0[j], (float)bf1[j]);
      v = fmaxf(v, __shfl_xor(v, 1, 64));
      pk_[j] = (_Float16)v;
    }
    if (!(l & 1))
      *(half8*)(phi + ((size_t)b*M_ + mrow)*C_ + c0) = pk_;
#pragma unroll
    for (int ds = 0; ds < 8; ++ds) {
      half8 af = *(const half8*)(gw16 + (size_t)(ds*16 + c16)*C_ + c0);
      acc[ds][0] = __builtin_amdgcn_mfma_f32_16x16x32_f16(af, bf0, acc[ds][0], 0, 0, 0);
      acc[ds][1] = __builtin_amdgcn_mfma_f32_16x16x32_f16(af, bf1, acc[ds][1], 0, 0, 0);
    }
  }

#pragma unroll
  for (int ds = 0; ds < 8; ++ds) {
#pragma unroll
    for (int r = 0; r < 4; ++r) {
      const int d = ds*16 + gq*4 + r;
      float v = fmaxf(acc[ds][0][r], acc[ds][1][r]);
      v = fmaxf(v, __shfl_xor(v, 1, 64));
      if (!(l & 1))
        gpool[((size_t)b*D_ + d)*M_ + mrow] = (_Float16)(v + g_b[d]);
    }
  }
}

// ---------------------------------------------------------------------------
// in-register P -> PV A-fragment build (xor16 / xor32 shuffle network)
// ---------------------------------------------------------------------------
__device__ __forceinline__ half8 build_pa(const float p0[4], const float p1[4], int gq) {
  unsigned d0 = pkrtz(p0[0], p0[1]);
  unsigned d1 = pkrtz(p0[2], p0[3]);
  unsigned e0 = pkrtz(p1[0], p1[1]);
  unsigned e1 = pkrtz(p1[2], p1[3]);
  unsigned D0 = __shfl_xor(d0, 16, 64), D1 = __shfl_xor(d1, 16, 64);
  unsigned E0 = __shfl_xor(e0, 16, 64), E1 = __shfl_xor(e1, 16, 64);
  const bool lo = gq < 2;
  unsigned s0 = lo ? e0 : d0, s1 = lo ? e1 : d1;
  unsigned s2 = lo ? E0 : D0, s3 = lo ? E1 : D1;
  unsigned R0 = __shfl_xor(s0, 32, 64), R1 = __shfl_xor(s1, 32, 64);
  unsigned R2 = __shfl_xor(s2, 32, 64), R3 = __shfl_xor(s3, 32, 64);
  uint4e u;
  u[0] = gq==0 ? d0 : gq==1 ? R2 : gq==2 ? R0 : E0;
  u[1] = gq==0 ? d1 : gq==1 ? R3 : gq==2 ? R1 : E1;
  u[2] = gq==0 ? D0 : gq==1 ? R0 : gq==2 ? R2 : e0;
  u[3] = gq==0 ? D1 : gq==1 ? R1 : gq==2 ? R3 : e1;
  return __builtin_bit_cast(half8, u);
}

// ---------------------------------------------------------------------------
// P3: flash attention v2. Swapped QK^T (S cols lane-local), in-register
// softmax + A-frag shuffle (no P LDS), 16B-column-major LDS (0 conflicts),
// global_load_lds dbuf staging + counted vmcnt(6), defer-max THR=8.
// ---------------------------------------------------------------------------
__global__ __launch_bounds__(256, 2) void attn_kernel(
    const float* __restrict__ x, const _Float16* __restrict__ phi,
    const _Float16* __restrict__ gpool, _Float16* __restrict__ y) {
  const int nt = blockIdx.x;           // 0..31
  const int b  = blockIdx.y;
  const int t  = threadIdx.x;
  const int w = t >> 6, l = t & 63, gq = l >> 4, c16 = l & 15;
  const int nw = nt*128 + w*32;

  // [o16 plane][row][16B]: phi: 32 planes x (32 m x 16B); gp: 4 planes x (128 d x 16B)
  __shared__ alignas(16) _Float16 phi_s[2][32*256];
  __shared__ alignas(16) _Float16 gp_s[2][128*32];

  // Q fragments (B-operand): rows nw + rt*16 + c16, K=256 in 8 kk-steps
  half8 qf[2][8];
#pragma unroll
  for (int rt = 0; rt < 2; ++rt) {
    const int nq = nw + rt*16 + c16;
#pragma unroll
    for (int kk = 0; kk < 8; ++kk) {
      const int cb = kk*32 + gq*8;
      half8 q;
#pragma unroll
      for (int j = 0; j < 8; ++j) q[j] = (_Float16)x[((size_t)b*C_ + cb + j)*N_ + nq];
      qf[rt][kk] = q;
    }
  }

  f32x4 yacc[2][8];
#pragma unroll
  for (int rt = 0; rt < 2; ++rt)
#pragma unroll
    for (int ds = 0; ds < 8; ++ds) yacc[rt][ds] = (f32x4){0.f,0.f,0.f,0.f};
  float m_run[2] = {-INFINITY, -INFINITY};
  float l_run[2] = {0.f, 0.f};

  const int lhi = l >> 5, l31 = l & 31;

  auto stage = [&](int buf, int ch2) {
    const int m0 = ch2 * 32;
    // phi chunk 16KB = 16 issues (4/wave). plane p = 2j+lhi, row m = l31.
#pragma unroll
    for (int jj = 0; jj < 4; ++jj) {
      const int j = w*4 + jj;
      const char* src = (const char*)phi + ((size_t)(b*M_ + m0 + l31))*512 + (2*j + lhi)*16;
      gl2lds16(src, (char*)&phi_s[buf][0] + j*1024);
    }
    // gp chunk 8KB = 8 issues (2/wave). plane = j>>1, d = (j&1)*64 + l.
#pragma unroll
    for (int jj = 0; jj < 2; ++jj) {
      const int j = w*2 + jj;
      const char* src = (const char*)gpool + (((size_t)(b*D_ + (j&1)*64 + l))*M_ + m0)*2 + (j>>1)*16;
      gl2lds16(src, (char*)&gp_s[buf][0] + j*1024);
    }
  };

  stage(0, 0);

  const char* pAbase = (const char*)&phi_s[0][0] + gq*512 + c16*16;
  const char* pBbase = (const char*)&gp_s[0][0] + gq*2048 + c16*16;

  for (int ch = 0; ch < NCH; ++ch) {
    const int cur = ch & 1;
    if (ch + 1 < NCH) {
      stage(cur ^ 1, ch + 1);
      asm volatile("s_waitcnt vmcnt(6)" ::: "memory");
    } else {
      asm volatile("s_waitcnt vmcnt(0)" ::: "memory");
    }
    __builtin_amdgcn_s_barrier();
    asm volatile("" ::: "memory");

    // ---- QK^T swapped: fS[rt][mt] = S[m = mt*16+gq*4+r][n-col = c16]
    f32x4 fS[2][2];
    fS[0][0] = (f32x4){0.f,0.f,0.f,0.f}; fS[0][1] = (f32x4){0.f,0.f,0.f,0.f};
    fS[1][0] = (f32x4){0.f,0.f,0.f,0.f}; fS[1][1] = (f32x4){0.f,0.f,0.f,0.f};
    const char* pA = pAbase + cur*16384;
    __builtin_amdgcn_s_setprio(1);
#pragma unroll
    for (int kk = 0; kk < 8; ++kk) {
      half8 a0 = *(const half8*)(pA + kk*2048);        // mt=0 rows
      half8 a1 = *(const half8*)(pA + kk*2048 + 256);  // mt=1 rows
      fS[0][0] = __builtin_amdgcn_mfma_f32_16x16x32_f16(a0, qf[0][kk], fS[0][0], 0, 0, 0);
      fS[1][0] = __builtin_amdgcn_mfma_f32_16x16x32_f16(a0, qf[1][kk], fS[1][0], 0, 0, 0);
      fS[0][1] = __builtin_amdgcn_mfma_f32_16x16x32_f16(a1, qf[0][kk], fS[0][1], 0, 0, 0);
      fS[1][1] = __builtin_amdgcn_mfma_f32_16x16x32_f16(a1, qf[1][kk], fS[1][1], 0, 0, 0);
    }
    __builtin_amdgcn_s_setprio(0);

    // ---- online softmax, per n-column (lane-local) + defer-max
    float cm[2];
#pragma unroll
    for (int rt = 0; rt < 2; ++rt) {
      float cmax = fS[rt][0][0];
#pragma unroll
      for (int mt = 0; mt < 2; ++mt)
#pragma unroll
        for (int r = 0; r < 4; ++r) cmax = fmaxf(cmax, fS[rt][mt][r]);
      cmax = fmaxf(cmax, __shfl_xor(cmax, 16, 64));
      cmax = fmaxf(cmax, __shfl_xor(cmax, 32, 64));
      cm[rt] = cmax;
    }
    const float grow = fmaxf(cm[0] - m_run[0], cm[1] - m_run[1]);
    if (__any(grow > 8.0f)) {     // slow path: rescale
#pragma unroll
      for (int rt = 0; rt < 2; ++rt) {
        const float mn = fmaxf(m_run[rt], cm[rt]);
        const float sc = __expf(m_run[rt] - mn);
        m_run[rt] = mn;
        l_run[rt] *= sc;
        const int sci = __float_as_int(sc);
#pragma unroll
        for (int r = 0; r < 4; ++r) {
          const float scn = __int_as_float(__builtin_amdgcn_ds_bpermute(4*(gq*4 + r), sci));
#pragma unroll
          for (int ds = 0; ds < 8; ++ds) yacc[rt][ds][r] *= scn;
        }
      }
    }
    half8 pa[2];
#pragma unroll
    for (int rt = 0; rt < 2; ++rt) {
      float p0[4], p1[4];
      float rs = 0.f;
#pragma unroll
      for (int r = 0; r < 4; ++r) {
        p0[r] = __expf(fS[rt][0][r] - m_run[rt]);
        p1[r] = __expf(fS[rt][1][r] - m_run[rt]);
        rs += p0[r] + p1[r];
      }
      rs += __shfl_xor(rs, 16, 64);
      rs += __shfl_xor(rs, 32, 64);
      l_run[rt] += rs;
      pa[rt] = build_pa(p0, p1, gq);
    }

    // ---- PV
    const char* pB = pBbase + cur*8192;
    __builtin_amdgcn_s_setprio(1);
#pragma unroll
    for (int ds = 0; ds < 8; ++ds) {
      half8 bv = *(const half8*)(pB + ds*256);
      yacc[0][ds] = __builtin_amdgcn_mfma_f32_16x16x32_f16(pa[0], bv, yacc[0][ds], 0, 0, 0);
      yacc[1][ds] = __builtin_amdgcn_mfma_f32_16x16x32_f16(pa[1], bv, yacc[1][ds], 0, 0, 0);
    }
    __builtin_amdgcn_s_setprio(0);

    asm volatile("" ::: "memory");
    __builtin_amdgcn_s_barrier();
    asm volatile("" ::: "memory");
  }

  // epilogue: broadcast 1/l from n=c16 lanes to (gq,r) rows, write y fp16
#pragma unroll
  for (int rt = 0; rt < 2; ++rt) {
    const float inv = 1.0f / l_run[rt];
    const int invi = __float_as_int(inv);
#pragma unroll
    for (int r = 0; r < 4; ++r) {
      const float invn = __int_as_float(__builtin_amdgcn_ds_bpermute(4*(gq*4 + r), invi));
      const int n = nw + rt*16 + gq*4 + r;
      _Float16* yr = y + ((size_t)b*N_ + n)*D_ + c16;
#pragma unroll
      for (int ds = 0; ds < 8; ++ds) yr[ds*16] = (_Float16)(yacc[rt][ds][r] * invn);
    }
  }
}

// ---------------------------------------------------------------------------
// P4a: W-conv recompute -> per-(block,channel) partial sum/sumsq. No atomics.
// ---------------------------------------------------------------------------
__global__ __launch_bounds__(256) void stats_partial_kernel(
    const _Float16* __restrict__ y, const _Float16* __restrict__ ww16,
    const float* __restrict__ w_b, float* __restrict__ psum,
    float* __restrict__ pssq) {
  const int nt = blockIdx.x, b = blockIdx.y, t = threadIdx.x;
  const int w = t >> 6, l = t & 63, g = l >> 4, c16 = l & 15;

  float s_acc[4][4], q_acc[4][4], wb_r[4][4];
#pragma unroll
  for (int cs = 0; cs < 4; ++cs)
#pragma unroll
    for (int r = 0; r < 4; ++r) {
      s_acc[cs][r] = 0.f; q_acc[cs][r] = 0.f;
      wb_r[cs][r] = w_b[w*64 + cs*16 + g*4 + r];
    }

  for (int nb = 0; nb < 4; ++nb) {
    const int n0 = nt*256 + nb*64;
    f32x4 acc[4][4];
#pragma unroll
    for (int a = 0; a < 4; ++a)
#pragma unroll
      for (int n = 0; n < 4; ++n) acc[a][n] = (f32x4){0.f,0.f,0.f,0.f};

#pragma unroll
    for (int kk = 0; kk < 4; ++kk) {
      const int d0 = kk*32 + g*8;
      half8 af[4];
#pragma unroll
      for (int cs = 0; cs < 4; ++cs)
        af[cs] = *(const half8*)(ww16 + (size_t)(w*64 + cs*16 + c16)*D_ + d0);
#pragma unroll
      for (int ns = 0; ns < 4; ++ns) {
        const int nn = n0 + ns*16 + c16;
        half8 bf = *(const half8*)&y[((size_t)b*N_ + nn)*D_ + d0];
#pragma unroll
        for (int cs = 0; cs < 4; ++cs)
          acc[cs][ns] = __builtin_amdgcn_mfma_f32_16x16x32_f16(af[cs], bf, acc[cs][ns], 0, 0, 0);
      }
    }
#pragma unroll
    for (int cs = 0; cs < 4; ++cs)
#pragma unroll
      for (int r = 0; r < 4; ++r) {
        const float wb = wb_r[cs][r];
#pragma unroll
        for (int ns = 0; ns < 4; ++ns) {
          const float v = acc[cs][ns][r] + wb;
          s_acc[cs][r] += v; q_acc[cs][r] += v*v;
        }
      }
  }

  const int blk = b*16 + nt;
#pragma unroll
  for (int cs = 0; cs < 4; ++cs)
#pragma unroll
    for (int r = 0; r < 4; ++r) {
      float s = s_acc[cs][r], q = q_acc[cs][r];
      s += __shfl_xor(s, 1, 64); s += __shfl_xor(s, 2, 64);
      s += __shfl_xor(s, 4, 64); s += __shfl_xor(s, 8, 64);
      q += __shfl_xor(q, 1, 64); q += __shfl_xor(q, 2, 64);
      q += __shfl_xor(q, 4, 64); q += __shfl_xor(q, 8, 64);
      if (c16 == 0) {
        const int c = w*64 + cs*16 + g*4 + r;
        psum[blk*C_ + c] = s;
        pssq[blk*C_ + c] = q;
      }
    }
}

// ---------------------------------------------------------------------------
// P4a2: reduce 256 partials -> bnsum/bnssq. grid 8 blocks x 256t.
// ---------------------------------------------------------------------------
__global__ __launch_bounds__(256) void stats_reduce_kernel(
    const float* __restrict__ psum, const float* __restrict__ pssq,
    float* __restrict__ bnsum, float* __restrict__ bnssq) {
  const int t = threadIdx.x;
  const int ci = t & 31, bi = t >> 5;
  const int c = blockIdx.x*32 + ci;
  float s = 0.f, q = 0.f;
  for (int k = 0; k < 32; ++k) {
    const int row = bi + k*8;
    s += psum[row*C_ + c];
    q += pssq[row*C_ + c];
  }
  __shared__ float rs[8][32], rq[8][32];
  rs[bi][ci] = s; rq[bi][ci] = q;
  __syncthreads();
  if (bi == 0) {
    float S = 0.f, Q = 0.f;
#pragma unroll
    for (int k2 = 0; k2 < 8; ++k2) { S += rs[k2][ci]; Q += rq[k2][ci]; }
    bnsum[c] = S; bnssq[c] = Q;
  }
}

// ---------------------------------------------------------------------------
// P4b: W-conv recompute (fp16 y) + BatchNorm + residual -> out[b][c][n] f32
// ---------------------------------------------------------------------------
__global__ __launch_bounds__(256) void wconv_bn_kernel(
    const _Float16* __restrict__ y, const _Float16* __restrict__ ww16,
    const float* __restrict__ w_b, const float* __restrict__ bnsum,
    const float* __restrict__ bnssq, const float* __restrict__ gamma,
    const float* __restrict__ beta, const float* __restrict__ x,
    float* __restrict__ out) {
  const int nt = blockIdx.x, b = blockIdx.y, t = threadIdx.x;
  const int w = t >> 6, l = t & 63, g = l >> 4, c16 = l & 15;
  const int n0 = nt*64;

  f32x4 acc[4][4];
#pragma unroll
  for (int a = 0; a < 4; ++a)
#pragma unroll
    for (int n = 0; n < 4; ++n) acc[a][n] = (f32x4){0.f,0.f,0.f,0.f};

#pragma unroll
  for (int kk = 0; kk < 4; ++kk) {
    const int d0 = kk*32 + g*8;
    half8 af[4];
#pragma unroll
    for (int cs = 0; cs < 4; ++cs)
      af[cs] = *(const half8*)(ww16 + (size_t)(w*64 + cs*16 + c16)*D_ + d0);
#pragma unroll
    for (int ns = 0; ns < 4; ++ns) {
      const int nn = n0 + ns*16 + c16;
      half8 bf = *(const half8*)&y[((size_t)b*N_ + nn)*D_ + d0];
#pragma unroll
      for (int cs = 0; cs < 4; ++cs)
        acc[cs][ns] = __builtin_amdgcn_mfma_f32_16x16x32_f16(af[cs], bf, acc[cs][ns], 0, 0, 0);
    }
  }

  const float inv_cnt = 1.0f / (float)((size_t)B_ * N_);
#pragma unroll
  for (int cs = 0; cs < 4; ++cs) {
#pragma unroll
    for (int r = 0; r < 4; ++r) {
      const int c = w*64 + cs*16 + g*4 + r;
      const float wb  = w_b[c];
      const float mean = bnsum[c] * inv_cnt;
      const float var  = bnssq[c] * inv_cnt - mean*mean;
      const float istd = rsqrtf(var + 1e-5f);
      const float ga = gamma[c], be = beta[c];
#pragma unroll
      for (int ns = 0; ns < 4; ++ns) {
        const int n = n0 + ns*16 + c16;
        const size_t idx = ((size_t)b*C_ + c)*N_ + n;
        const float v = acc[cs][ns][r] + wb;
        out[idx] = (v - mean)*istd*ga + be + x[idx];
      }
    }
  }
}

// ---------------------------------------------------------------------------
extern "C" void kernel_launch(void* const* d_in, const int* in_sizes, int n_in,
                              void* d_out, int out_size, void* d_ws, size_t ws_size,
                              hipStream_t stream) {
  const float* x     = (const float*)d_in[0];
  const float* g_w   = (const float*)d_in[1];
  const float* g_b   = (const float*)d_in[2];
  const float* w_w   = (const float*)d_in[3];
  const float* w_b   = (const float*)d_in[4];
  const float* gamma = (const float*)d_in[5];
  const float* beta  = (const float*)d_in[6];
  float* out = (float*)d_out;

  char* ws = (char*)d_ws;
  _Float16* phi   = (_Float16*)(ws + WS_PHI);
  _Float16* gpool = (_Float16*)(ws + WS_GPOOL);
  _Float16* yb    = (_Float16*)(ws + WS_Y);
  float*    bnsum = (float*)(ws + WS_BNSUM);
  float*    bnssq = (float*)(ws + WS_BNSSQ);
  float*    psum  = (float*)(ws + WS_PSUM);
  float*    pssq  = (float*)(ws + WS_PSSQ);
  _Float16* gw16  = (_Float16*)(ws + WS_GW16);
  _Float16* ww16  = (_Float16*)(ws + WS_WW16);

  conv16_kernel<<<128, 256, 0, stream>>>(g_w, w_w, gw16, ww16);
  fused_pre_kernel<<<dim3(32, 16), 256, 0, stream>>>(x, gw16, g_b, phi, gpool);
  attn_kernel<<<dim3(32, 16), 256, 0, stream>>>(x, phi, gpool, yb);
  stats_partial_kernel<<<dim3(16, 16), 256, 0, stream>>>(yb, ww16, w_b, psum, pssq);
  stats_reduce_kernel<<<8, 256, 0, stream>>>(psum, pssq, bnsum, bnssq);
  wconv_bn_kernel<<<dim3(64, 16), 256, 0, stream>>>(yb, ww16, w_b, bnsum, bnssq, gamma, beta, x, out);
}